// Round 1
// 641.410 us; speedup vs baseline: 1.2418x; 1.2418x over previous
//
#include <hip/hip_runtime.h>
#include <math.h>

// SpectralConv3d: direct truncated DFTs.
// x: (8,32,32,96,96) f32; Wr/Wi: (32,32,8,16,16) f32; out: (8,32,32,96,96) f32.
// Pipeline:
//   k_tw    : build twiddle tables once into workspace (cos/sin, pad-100 rows)
//   k_fwd2d : per (b,c,t): W-DFT (96->16) + H-DFT (96->16), 2x48-row strips -> X2
//   k_fwdT  : T-DFT (32->8)                                                -> X3
//   k_mix   : out_ft = scale * sum_c X3 * (Wr+iWi)   (grid 2048)           -> Cf
//   k_inv   : fused invT (8->32, per-block t) + H expand (16->96) + c2r W  -> out
// Ortho norms folded into k_mix: 1/(T*H*W).

#define B_   8
#define CIN  32
#define COUT 32
#define T_   32
#define H_   96
#define W_   96
#define MT   8
#define MS   16

// ---------------- twiddle tables (once per call, trivial) ----------------
// tw96[k*100+n]        = cos(2*pi*(k*n mod 96)/96), k<16, n<96 (pad 100)
// tw96[1600 + k*100+n] = sin(...)
// tw32[p] = cos(2*pi*p/32), tw32[32+p] = sin(...), p<32
__global__ void k_tw(float* __restrict__ tw96, float* __restrict__ tw32) {
  int i = blockIdx.x * 256 + threadIdx.x;
  if (i < 1600) {
    int k = i / 100, n = i - k * 100;
    float c = 0.f, s = 0.f;
    if (n < 96) {
      int p = (k * n) % 96;
      float ang = (float)p * (6.2831853071795864769f / 96.0f);
      sincosf(ang, &s, &c);
    }
    tw96[i] = c;
    tw96[1600 + i] = s;
  } else if (i < 1632) {
    int j = i - 1600;
    float ang = (float)j * (6.2831853071795864769f / 32.0f);
    float s, c;
    sincosf(ang, &s, &c);
    tw32[j] = c;
    tw32[32 + j] = s;
  }
}

// ---------------- K1: forward W + H DFT per (b,c,t), 2x48-row strips ----------------
// LDS 38528 B -> 4 blocks/CU.  Stage1: thread=(kw=tid>>4, hg=tid&15) owns 3 rows x 1 kw,
// 5 ds_read_b128 per 24 FMA.  Stage2: thread=(kh=tid>>4, kw=tid&15), acc over 96 h.
__global__ __launch_bounds__(256) void k_fwd2d(const float* __restrict__ x,
                                               const float* __restrict__ twg,
                                               float2* __restrict__ X2) {
  __shared__ __align__(16) float tw[3200];      // [0,1600) cos | [1600,3200) sin, stride 100
  __shared__ __align__(16) float xs[48 * 100];  // strip, pad 100 (rows stay 16B-aligned)
  __shared__ __align__(16) float2 y2s[48 * 17]; // stage1 out [h_local][kw], pad 17
  const int tid = threadIdx.x;
  const int bct = blockIdx.x;
  const float* xg = x + (size_t)bct * (H_ * W_);
  const float4* xg4 = (const float4*)xg;

  // tw table from global (L2/L3-hot, 800 float4)
  {
    const float4* g4 = (const float4*)twg;
    float4* t4 = (float4*)tw;
#pragma unroll
    for (int i = 0; i < 4; ++i) {
      int j = tid + i * 256;
      if (j < 800) t4[j] = g4[j];
    }
  }
  // strip 0 (rows 0..47) -> xs
  for (int i4 = tid; i4 < 1152; i4 += 256) {
    float4 v = xg4[i4];
    int h = i4 / 24, w4 = i4 - h * 24;
    *(float4*)&xs[h * 100 + 4 * w4] = v;
  }
  __syncthreads();

  const float* twc = tw;
  const float* tws = tw + 1600;
  const int kw1 = tid >> 4;  // stage1 kw
  const int hg  = tid & 15;  // stage1 row group (3 rows)
  const int kh2 = tid >> 4;  // stage2 kh
  const int kw2 = tid & 15;  // stage2 kw
  float s2r = 0.f, s2i = 0.f;  // stage2 accumulator (one (kh,kw) per thread)

  // stage 1: y[h][kw] = sum_w x[h][w] e^{-2pi i kw w/96}
  auto stage1 = [&]() {
    float a0r = 0.f, a1r = 0.f, a2r = 0.f;
    float p0i = 0.f, p1i = 0.f, p2i = 0.f;  // +sum x*s; negate at store
    const float4* xr0 = (const float4*)&xs[(3 * hg + 0) * 100];
    const float4* xr1 = (const float4*)&xs[(3 * hg + 1) * 100];
    const float4* xr2 = (const float4*)&xs[(3 * hg + 2) * 100];
    const float4* c4 = (const float4*)&twc[kw1 * 100];
    const float4* s4 = (const float4*)&tws[kw1 * 100];
#pragma unroll 4
    for (int w4 = 0; w4 < 24; ++w4) {
      float4 c = c4[w4], s = s4[w4];
      float4 v0 = xr0[w4], v1 = xr1[w4], v2 = xr2[w4];
      a0r = fmaf(v0.x, c.x, fmaf(v0.y, c.y, fmaf(v0.z, c.z, fmaf(v0.w, c.w, a0r))));
      p0i = fmaf(v0.x, s.x, fmaf(v0.y, s.y, fmaf(v0.z, s.z, fmaf(v0.w, s.w, p0i))));
      a1r = fmaf(v1.x, c.x, fmaf(v1.y, c.y, fmaf(v1.z, c.z, fmaf(v1.w, c.w, a1r))));
      p1i = fmaf(v1.x, s.x, fmaf(v1.y, s.y, fmaf(v1.z, s.z, fmaf(v1.w, s.w, p1i))));
      a2r = fmaf(v2.x, c.x, fmaf(v2.y, c.y, fmaf(v2.z, c.z, fmaf(v2.w, c.w, a2r))));
      p2i = fmaf(v2.x, s.x, fmaf(v2.y, s.y, fmaf(v2.z, s.z, fmaf(v2.w, s.w, p2i))));
    }
    y2s[(3 * hg + 0) * 17 + kw1] = make_float2(a0r, -p0i);
    y2s[(3 * hg + 1) * 17 + kw1] = make_float2(a1r, -p1i);
    y2s[(3 * hg + 2) * 17 + kw1] = make_float2(a2r, -p2i);
  };

  // stage 2: X2[kh][kw] += sum_{h in strip} y[h][kw] e^{-2pi i kh h/96}
  auto stage2 = [&](int strip) {
    const float4* c4 = (const float4*)&twc[kh2 * 100 + strip * 48];
    const float4* s4 = (const float4*)&tws[kh2 * 100 + strip * 48];
#pragma unroll 4
    for (int h4 = 0; h4 < 12; ++h4) {
      float4 c = c4[h4], s = s4[h4];
      float2 v0 = y2s[(4 * h4 + 0) * 17 + kw2];
      float2 v1 = y2s[(4 * h4 + 1) * 17 + kw2];
      float2 v2 = y2s[(4 * h4 + 2) * 17 + kw2];
      float2 v3 = y2s[(4 * h4 + 3) * 17 + kw2];
      // (vr + i vi)(c - i s)
      s2r = fmaf(v0.x, c.x, fmaf(v0.y, s.x, s2r)); s2i = fmaf(v0.y, c.x, fmaf(-v0.x, s.x, s2i));
      s2r = fmaf(v1.x, c.y, fmaf(v1.y, s.y, s2r)); s2i = fmaf(v1.y, c.y, fmaf(-v1.x, s.y, s2i));
      s2r = fmaf(v2.x, c.z, fmaf(v2.y, s.z, s2r)); s2i = fmaf(v2.y, c.z, fmaf(-v2.x, s.z, s2i));
      s2r = fmaf(v3.x, c.w, fmaf(v3.y, s.w, s2r)); s2i = fmaf(v3.y, c.w, fmaf(-v3.x, s.w, s2i));
    }
  };

  // ---- strip 0 ----
  stage1();
  __syncthreads();
  // prefetch strip 1 (issued before stage2 math -> HBM latency hidden)
  float4 p0 = xg4[1152 + tid];
  float4 p1 = xg4[1408 + tid];
  float4 p2 = xg4[1664 + tid];
  float4 p3 = xg4[1920 + tid];
  float4 p4 = make_float4(0.f, 0.f, 0.f, 0.f);
  if (tid < 128) p4 = xg4[2176 + tid];
  stage2(0);
  {
    int r, h, w4;
    r = tid;        h = r / 24; w4 = r - h * 24; *(float4*)&xs[h * 100 + 4 * w4] = p0;
    r = tid + 256;  h = r / 24; w4 = r - h * 24; *(float4*)&xs[h * 100 + 4 * w4] = p1;
    r = tid + 512;  h = r / 24; w4 = r - h * 24; *(float4*)&xs[h * 100 + 4 * w4] = p2;
    r = tid + 768;  h = r / 24; w4 = r - h * 24; *(float4*)&xs[h * 100 + 4 * w4] = p3;
    if (tid < 128) { r = tid + 1024; h = r / 24; w4 = r - h * 24; *(float4*)&xs[h * 100 + 4 * w4] = p4; }
  }
  __syncthreads();
  // ---- strip 1 ----
  stage1();
  __syncthreads();
  stage2(1);

  X2[(size_t)bct * 256 + tid] = make_float2(s2r, s2i);
}

// ---------------- K2: forward T DFT per (b,c) (unchanged) ----------------
__global__ __launch_bounds__(256) void k_fwdT(const float2* __restrict__ X2,
                                              float2* __restrict__ X3) {
  __shared__ float twtc[MT * T_], twts[MT * T_];
  const int tid = threadIdx.x;
  const int bc = blockIdx.x;
  {
    int kt = tid / T_, t = tid - kt * T_;
    int p = (kt * t) & 31;
    float ang = (float)p * (6.2831853071795864769f / 32.0f);
    float s, c; sincosf(ang, &s, &c);
    twtc[tid] = c; twts[tid] = s;
  }
  __syncthreads();
  float ar[MT], ai[MT];
#pragma unroll
  for (int k = 0; k < MT; k++) { ar[k] = 0.f; ai[k] = 0.f; }
  const float2* src = X2 + (size_t)bc * (T_ * 256);
  for (int t = 0; t < T_; t++) {
    float2 v = src[t * 256 + tid];
#pragma unroll
    for (int k = 0; k < MT; k++) {
      float c = twtc[k * T_ + t], s = twts[k * T_ + t];
      ar[k] = fmaf(v.x, c, fmaf(v.y, s, ar[k]));   // e^{-i}
      ai[k] = fmaf(v.y, c, fmaf(-v.x, s, ai[k]));
    }
  }
  float2* dst = X3 + (size_t)bc * (MT * 256);
#pragma unroll
  for (int k = 0; k < MT; k++) dst[k * 256 + tid] = make_float2(ar[k], ai[k]);
}

// ---------------- K3: channel mix, grid (b,d,chunk) = 2048 blocks ----------------
__global__ __launch_bounds__(256) void k_mix(const float2* __restrict__ X3,
                                             const float* __restrict__ Wr,
                                             const float* __restrict__ Wi,
                                             float2* __restrict__ Cf) {
  const int tid = threadIdx.x;
  const int b = blockIdx.x >> 8;
  const int d = (blockIdx.x >> 3) & 31;
  const int m = (blockIdx.x & 7) * 256 + tid;
  const float scale = 1.0f / (float)(T_ * H_ * W_);  // combined ortho factor
  float ar = 0.f, ai = 0.f;
  for (int c = 0; c < CIN; c++) {
    float2 xv = X3[((size_t)(b * CIN + c)) * 2048 + m];
    float wr = Wr[((size_t)(c * COUT + d)) * 2048 + m];
    float wi = Wi[((size_t)(c * COUT + d)) * 2048 + m];
    ar = fmaf(xv.x, wr, fmaf(-xv.y, wi, ar));
    ai = fmaf(xv.x, wi, fmaf(xv.y, wr, ai));
  }
  Cf[((size_t)(b * COUT + d)) * 2048 + m] = make_float2(ar * scale, ai * scale);
}

// ---------------- K5: fused inverse (T expand + H expand + c2r W) per (b,d,t) ----------------
// LDS 28032 B -> 5 blocks/CU.  invT done in-block (D tensor eliminated).
__global__ __launch_bounds__(256) void k_inv(const float2* __restrict__ Cf,
                                             const float* __restrict__ twg,
                                             const float* __restrict__ tw32g,
                                             float* __restrict__ out) {
  __shared__ __align__(16) float tw[3200];
  __shared__ __align__(16) float2 dm[16 * 17];   // [kh][kw] pad 17
  __shared__ __align__(16) float2 g2[96 * 17];   // [h][kw]  pad 17
  const int tid = threadIdx.x;
  const int bdt = blockIdx.x;
  const int bd = bdt >> 5;
  const int t = bdt & 31;

  {
    const float4* g4 = (const float4*)twg;
    float4* t4 = (float4*)tw;
#pragma unroll
    for (int i = 0; i < 4; ++i) {
      int j = tid + i * 256;
      if (j < 800) t4[j] = g4[j];
    }
  }

  // fused invT: dm[m] = sum_kt Cf[bd,kt,m] * e^{+2pi i kt t/32}
  {
    float dr = 0.f, di = 0.f;
    const float2* src = Cf + (size_t)bd * 2048;
#pragma unroll
    for (int kt = 0; kt < 8; ++kt) {
      int p = (kt * t) & 31;
      float c = tw32g[p], s = tw32g[32 + p];      // uniform -> scalar loads
      float2 v = src[kt * 256 + tid];
      dr = fmaf(v.x, c, fmaf(-v.y, s, dr));
      di = fmaf(v.x, s, fmaf(v.y, c, di));
    }
    dm[(tid >> 4) * 17 + (tid & 15)] = make_float2(dr, di);
  }
  __syncthreads();

  const float* twc = tw;
  const float* tws = tw + 1600;

  // stage A: g2[h][kw] = sum_kh dm[kh][kw] e^{+2pi i kh h/96}; thread=(hg,kw), 4 rows/pass
  {
    const int hg = tid >> 4, kw = tid & 15;
    for (int pass = 0; pass < 2; ++pass) {
      if (pass == 1 && hg >= 8) continue;        // wave-uniform
      const int h0 = (pass == 0) ? (4 * hg) : (64 + 4 * hg);
      float ar[4] = {0.f, 0.f, 0.f, 0.f}, ai[4] = {0.f, 0.f, 0.f, 0.f};
#pragma unroll 4
      for (int kh = 0; kh < 16; ++kh) {
        float2 v = dm[kh * 17 + kw];
        float4 c = *(const float4*)&twc[kh * 100 + h0];
        float4 s = *(const float4*)&tws[kh * 100 + h0];
        ar[0] = fmaf(v.x, c.x, fmaf(-v.y, s.x, ar[0])); ai[0] = fmaf(v.x, s.x, fmaf(v.y, c.x, ai[0]));
        ar[1] = fmaf(v.x, c.y, fmaf(-v.y, s.y, ar[1])); ai[1] = fmaf(v.x, s.y, fmaf(v.y, c.y, ai[1]));
        ar[2] = fmaf(v.x, c.z, fmaf(-v.y, s.z, ar[2])); ai[2] = fmaf(v.x, s.z, fmaf(v.y, c.z, ai[2]));
        ar[3] = fmaf(v.x, c.w, fmaf(-v.y, s.w, ar[3])); ai[3] = fmaf(v.x, s.w, fmaf(v.y, c.w, ai[3]));
      }
#pragma unroll
      for (int q = 0; q < 4; ++q) g2[(h0 + q) * 17 + kw] = make_float2(ar[q], ai[q]);
    }
  }
  __syncthreads();

  // stage B: out[h][w] = Re(g2[h][0]) + 2*sum_{kw>=1}(gr cos - gi sin)
  // thread=(hg2=tid>>3 owns 3 rows, wq=tid&7), 3 passes over w
  {
    const int hg2 = tid >> 3, wq = tid & 7;
    const int h0 = 3 * hg2;
    float* orow = out + (size_t)bdt * (H_ * W_);
    for (int p = 0; p < 3; ++p) {
      const int w4 = p * 8 + wq;
      float acc0[4] = {0.f, 0.f, 0.f, 0.f};
      float acc1[4] = {0.f, 0.f, 0.f, 0.f};
      float acc2[4] = {0.f, 0.f, 0.f, 0.f};
#pragma unroll 5
      for (int kw = 1; kw < 16; ++kw) {
        float4 c = *(const float4*)&twc[kw * 100 + 4 * w4];
        float4 s = *(const float4*)&tws[kw * 100 + 4 * w4];
        float2 gA = g2[(h0 + 0) * 17 + kw];
        float2 gB = g2[(h0 + 1) * 17 + kw];
        float2 gC = g2[(h0 + 2) * 17 + kw];
        acc0[0] = fmaf(gA.x, c.x, fmaf(-gA.y, s.x, acc0[0]));
        acc0[1] = fmaf(gA.x, c.y, fmaf(-gA.y, s.y, acc0[1]));
        acc0[2] = fmaf(gA.x, c.z, fmaf(-gA.y, s.z, acc0[2]));
        acc0[3] = fmaf(gA.x, c.w, fmaf(-gA.y, s.w, acc0[3]));
        acc1[0] = fmaf(gB.x, c.x, fmaf(-gB.y, s.x, acc1[0]));
        acc1[1] = fmaf(gB.x, c.y, fmaf(-gB.y, s.y, acc1[1]));
        acc1[2] = fmaf(gB.x, c.z, fmaf(-gB.y, s.z, acc1[2]));
        acc1[3] = fmaf(gB.x, c.w, fmaf(-gB.y, s.w, acc1[3]));
        acc2[0] = fmaf(gC.x, c.x, fmaf(-gC.y, s.x, acc2[0]));
        acc2[1] = fmaf(gC.x, c.y, fmaf(-gC.y, s.y, acc2[1]));
        acc2[2] = fmaf(gC.x, c.z, fmaf(-gC.y, s.z, acc2[2]));
        acc2[3] = fmaf(gC.x, c.w, fmaf(-gC.y, s.w, acc2[3]));
      }
      float gA0 = g2[(h0 + 0) * 17].x;
      float gB0 = g2[(h0 + 1) * 17].x;
      float gC0 = g2[(h0 + 2) * 17].x;
      float4 o0, o1, o2;
      o0.x = fmaf(2.f, acc0[0], gA0); o0.y = fmaf(2.f, acc0[1], gA0);
      o0.z = fmaf(2.f, acc0[2], gA0); o0.w = fmaf(2.f, acc0[3], gA0);
      o1.x = fmaf(2.f, acc1[0], gB0); o1.y = fmaf(2.f, acc1[1], gB0);
      o1.z = fmaf(2.f, acc1[2], gB0); o1.w = fmaf(2.f, acc1[3], gB0);
      o2.x = fmaf(2.f, acc2[0], gC0); o2.y = fmaf(2.f, acc2[1], gC0);
      o2.z = fmaf(2.f, acc2[2], gC0); o2.w = fmaf(2.f, acc2[3], gC0);
      *(float4*)&orow[(h0 + 0) * 96 + 4 * w4] = o0;
      *(float4*)&orow[(h0 + 1) * 96 + 4 * w4] = o1;
      *(float4*)&orow[(h0 + 2) * 96 + 4 * w4] = o2;
    }
  }
}

extern "C" void kernel_launch(void* const* d_in, const int* in_sizes, int n_in,
                              void* d_out, int out_size, void* d_ws, size_t ws_size,
                              hipStream_t stream) {
  const float* x  = (const float*)d_in[0];
  const float* Wr = (const float*)d_in[1];
  const float* Wi = (const float*)d_in[2];
  float* out = (float*)d_out;

  // workspace (float2 units): X2 2097152 | X3 524288 | Cf 524288 | tw96 3200f | tw32 64f
  float2* X2 = (float2*)d_ws;
  float2* X3 = X2 + 2097152;
  float2* Cf = X3 + 524288;
  float* twg   = (float*)(Cf + 524288);
  float* tw32g = twg + 3200;

  k_tw   <<<7, 256, 0, stream>>>(twg, tw32g);
  k_fwd2d<<<B_ * CIN * T_,  256, 0, stream>>>(x, twg, X2);
  k_fwdT <<<B_ * CIN,       256, 0, stream>>>(X2, X3);
  k_mix  <<<B_ * COUT * 8,  256, 0, stream>>>(X3, Wr, Wi, Cf);
  k_inv  <<<B_ * COUT * T_, 256, 0, stream>>>(Cf, twg, tw32g, out);
}